// Round 1
// baseline (5595.036 us; speedup 1.0000x reference)
//
#include <hip/hip_runtime.h>
#include <hip/hip_bf16.h>

#define DEVFN __device__ __forceinline__

constexpr int B = 4, T = 128, C = 8, HH = 32, WW = 32, K = 9, HID = 64;
constexpr int HW = HH * WW;          // 1024
constexpr int BT = B * T;            // 512
constexpr int IN_CH = 3 * C + 1;     // 25
constexpr int OUT_CH = C + 1;        // 9
constexpr size_t Z_SIZE = (size_t)BT * C * HW;  // 4,194,304 floats (z_hat)

// ---------------------------------------------------------------------------
// helpers
// ---------------------------------------------------------------------------
DEVFN void interp_params(const int* __restrict__ idx, int b, int t,
                         int& t0, int& t1, float& ar, float& a) {
  int v[K];
#pragma unroll
  for (int k = 0; k < K; ++k) v[k] = idx[b * K + k];
  // insertion sort (reference sorts idx; input is already sorted but be exact)
#pragma unroll
  for (int i = 1; i < K; ++i) {
    int key = v[i];
    int j = i - 1;
    while (j >= 0 && v[j] > key) { v[j + 1] = v[j]; --j; }
    v[j + 1] = key;
  }
  int cnt = 0;
#pragma unroll
  for (int k = 0; k < K; ++k) cnt += (v[k] <= t) ? 1 : 0;
  int seg = min(max(cnt - 1, 0), K - 2);
  t0 = v[seg];
  t1 = v[seg + 1];
  ar = (float)(t - t0) / (float)max(t1 - t0, 1);
  a = fminf(fmaxf(ar, 0.f), 1.f);
}

DEVFN float silu_f(float x) { return x / (1.f + expf(-x)); }
DEVFN float sigmoid_f(float x) { return 1.f / (1.f + expf(-x)); }

// ---------------------------------------------------------------------------
// prep: build res_in = concat([z_base, z0, z1, alpha]) as bf16, NCHW per image
// ---------------------------------------------------------------------------
__global__ __launch_bounds__(256) void prep_kernel(
    const float* __restrict__ latents, const int* __restrict__ idx,
    __hip_bfloat16* __restrict__ res_in) {
  int img = blockIdx.x;            // b*T + t
  int b = img >> 7, t = img & 127; // T = 128
  int t0, t1;
  float ar, a;
  interp_params(idx, b, t, t0, t1, ar, a);
  const float* z0 = latents + ((size_t)b * T + t0) * C * HW;
  const float* z1 = latents + ((size_t)b * T + t1) * C * HW;
  __hip_bfloat16* o = res_in + (size_t)img * IN_CH * HW;
  for (int e = threadIdx.x; e < C * HW; e += blockDim.x) {
    float v0 = z0[e], v1 = z1[e];
    float zb = (1.f - a) * v0 + a * v1;
    o[e] = __float2bfloat16(zb);                // ch 0..7  : z_base
    o[C * HW + e] = __float2bfloat16(v0);       // ch 8..15 : z0
    o[2 * C * HW + e] = __float2bfloat16(v1);   // ch16..23 : z1
  }
  __hip_bfloat16 ab = __float2bfloat16(a);
  for (int e = threadIdx.x; e < HW; e += blockDim.x)
    o[3 * C * HW + e] = ab;                     // ch24 : t_chan
}

// ---------------------------------------------------------------------------
// direct 3x3 SAME conv, bf16 in/out, fp32 accum.
// grid = (BT, OC/OCT), block = 256 (each thread owns 4 pixels).
// LDS stages 8 input channels (with halo) + the weight slice.
// ---------------------------------------------------------------------------
template <int IC, int OC, int OCT, bool SILU, bool RESID>
__global__ __launch_bounds__(256) void conv3x3_kernel(
    const __hip_bfloat16* __restrict__ in, const float* __restrict__ w,
    const float* __restrict__ bias, __hip_bfloat16* __restrict__ out,
    const __hip_bfloat16* __restrict__ resid) {
  constexpr int ICH = 8;
  __shared__ float sIn[ICH][34][34];
  __shared__ float sW[ICH * 9][OCT];

  const int img = blockIdx.x;
  const int ocBase = blockIdx.y * OCT;
  const int tid = threadIdx.x;
  const __hip_bfloat16* inImg = in + (size_t)img * IC * HW;

  float acc[OCT][4];
#pragma unroll
  for (int o = 0; o < OCT; ++o)
#pragma unroll
    for (int i = 0; i < 4; ++i) acc[o][i] = 0.f;

  int px[4], py[4];
#pragma unroll
  for (int i = 0; i < 4; ++i) {
    int p = tid + i * 256;
    py[i] = p >> 5;
    px[i] = p & 31;
  }

  for (int c0 = 0; c0 < IC; c0 += ICH) {
    const int cn = min(ICH, IC - c0);
    __syncthreads();
    // stage input chunk with halo (zero-padded SAME)
    for (int e = tid; e < cn * 34 * 34; e += 256) {
      int c = e / 1156;
      int r = e - c * 1156;
      int yy = r / 34;
      int xx = r - yy * 34;
      int y = yy - 1, x = xx - 1;
      float v = 0.f;
      if ((unsigned)y < 32u && (unsigned)x < 32u)
        v = __bfloat162float(inImg[(c0 + c) * HW + y * 32 + x]);
      sIn[c][yy][xx] = v;
    }
    // stage weight slice [ic][tap][oc]
    for (int e = tid; e < cn * 9 * OCT; e += 256) {
      int ic = e / (9 * OCT);
      int r = e - ic * (9 * OCT);
      int tap = r / OCT;
      int o = r - tap * OCT;
      sW[ic * 9 + tap][o] = w[((size_t)(ocBase + o) * IC + (c0 + ic)) * 9 + tap];
    }
    __syncthreads();

    for (int ic = 0; ic < cn; ++ic) {
#pragma unroll
      for (int ky = 0; ky < 3; ++ky)
#pragma unroll
        for (int kx = 0; kx < 3; ++kx) {
          float wv[OCT];
#pragma unroll
          for (int o = 0; o < OCT; ++o) wv[o] = sW[ic * 9 + ky * 3 + kx][o];
#pragma unroll
          for (int i = 0; i < 4; ++i) {
            float iv = sIn[ic][py[i] + ky][px[i] + kx];
#pragma unroll
            for (int o = 0; o < OCT; ++o) acc[o][i] = fmaf(wv[o], iv, acc[o][i]);
          }
        }
    }
  }

  // epilogue
#pragma unroll
  for (int o = 0; o < OCT; ++o) {
    float bv = bias[ocBase + o];
#pragma unroll
    for (int i = 0; i < 4; ++i) {
      int p = tid + i * 256;
      float val = acc[o][i] + bv;
      if (SILU) val = silu_f(val);
      if (RESID)
        val += __bfloat162float(resid[(size_t)img * OC * HW + (ocBase + o) * HW + p]);
      out[(size_t)img * OC * HW + (ocBase + o) * HW + p] = __float2bfloat16(val);
    }
  }
}

// ---------------------------------------------------------------------------
// final conv (64 -> 9) fused with z_hat / conf epilogue. grid = (BT), OCT = 9.
// z_base recomputed in fp32 from latents (exact), residual damped by a(1-a).
// ---------------------------------------------------------------------------
__global__ __launch_bounds__(256) void conv_final_kernel(
    const __hip_bfloat16* __restrict__ hin, const float* __restrict__ w,
    const float* __restrict__ bias, const float* __restrict__ latents,
    const int* __restrict__ idx, float* __restrict__ dout) {
  constexpr int IC = HID;
  constexpr int OCT = OUT_CH;  // 9
  constexpr int ICH = 8;
  __shared__ float sIn[ICH][34][34];
  __shared__ float sW[ICH * 9][OCT];

  const int img = blockIdx.x;
  const int tid = threadIdx.x;
  const __hip_bfloat16* inImg = hin + (size_t)img * IC * HW;

  float acc[OCT][4];
#pragma unroll
  for (int o = 0; o < OCT; ++o)
#pragma unroll
    for (int i = 0; i < 4; ++i) acc[o][i] = 0.f;

  int px[4], py[4];
#pragma unroll
  for (int i = 0; i < 4; ++i) {
    int p = tid + i * 256;
    py[i] = p >> 5;
    px[i] = p & 31;
  }

  for (int c0 = 0; c0 < IC; c0 += ICH) {
    const int cn = ICH;  // 64 divisible by 8
    __syncthreads();
    for (int e = tid; e < cn * 34 * 34; e += 256) {
      int c = e / 1156;
      int r = e - c * 1156;
      int yy = r / 34;
      int xx = r - yy * 34;
      int y = yy - 1, x = xx - 1;
      float v = 0.f;
      if ((unsigned)y < 32u && (unsigned)x < 32u)
        v = __bfloat162float(inImg[(c0 + c) * HW + y * 32 + x]);
      sIn[c][yy][xx] = v;
    }
    for (int e = tid; e < cn * 9 * OCT; e += 256) {
      int ic = e / (9 * OCT);
      int r = e - ic * (9 * OCT);
      int tap = r / OCT;
      int o = r - tap * OCT;
      sW[ic * 9 + tap][o] = w[((size_t)o * IC + (c0 + ic)) * 9 + tap];
    }
    __syncthreads();

    for (int ic = 0; ic < cn; ++ic) {
#pragma unroll
      for (int ky = 0; ky < 3; ++ky)
#pragma unroll
        for (int kx = 0; kx < 3; ++kx) {
          float wv[OCT];
#pragma unroll
          for (int o = 0; o < OCT; ++o) wv[o] = sW[ic * 9 + ky * 3 + kx][o];
#pragma unroll
          for (int i = 0; i < 4; ++i) {
            float iv = sIn[ic][py[i] + ky][px[i] + kx];
#pragma unroll
            for (int o = 0; o < OCT; ++o) acc[o][i] = fmaf(wv[o], iv, acc[o][i]);
          }
        }
    }
  }

  // fused final epilogue
  const int b = img >> 7, t = img & 127;
  int t0, t1;
  float ar, a;
  interp_params(idx, b, t, t0, t1, ar, a);
  const bool interior = (ar > 0.f) && (ar < 1.f);
  const float aa = a * (1.f - a);
  const float* z0p = latents + ((size_t)b * T + t0) * C * HW;
  const float* z1p = latents + ((size_t)b * T + t1) * C * HW;

#pragma unroll
  for (int i = 0; i < 4; ++i) {
    int p = tid + i * 256;
#pragma unroll
    for (int c = 0; c < C; ++c) {
      float res = acc[c][i] + bias[c];
      float v0 = z0p[c * HW + p], v1 = z1p[c * HW + p];
      float zb = (1.f - a) * v0 + a * v1;
      dout[((size_t)img * C + c) * HW + p] = zb + aa * res;
    }
    float unc = sigmoid_f(acc[C][i] + bias[C]);
    float conf = interior ? fminf(fmaxf(1.f - unc, 0.f), 1.f) : 1.f;
    dout[Z_SIZE + (size_t)img * HW + p] = conf;
  }
}

// ---------------------------------------------------------------------------
// launch
// ---------------------------------------------------------------------------
extern "C" void kernel_launch(void* const* d_in, const int* in_sizes, int n_in,
                              void* d_out, int out_size, void* d_ws,
                              size_t ws_size, hipStream_t stream) {
  const float* latents = (const float*)d_in[0];
  const int* idx = (const int*)d_in[1];
  const float* w_in = (const float*)d_in[2];
  const float* b_in = (const float*)d_in[3];
  const float* w1s = (const float*)d_in[4];
  const float* b1s = (const float*)d_in[5];
  const float* w2s = (const float*)d_in[6];
  const float* b2s = (const float*)d_in[7];
  const float* w_out = (const float*)d_in[8];
  const float* b_out = (const float*)d_in[9];
  float* dout = (float*)d_out;

  // workspace layout (needs 160,432,128 bytes):
  //   H   : [0, 64 MiB)           bf16 512x64x32x32
  //   U   : [64 MiB, 128 MiB)     bf16 512x64x32x32
  //   Rin : [128 MiB, +25 MiB)    bf16 512x25x32x32
  char* ws = (char*)d_ws;
  __hip_bfloat16* Hbuf = (__hip_bfloat16*)ws;
  __hip_bfloat16* Ubuf = (__hip_bfloat16*)(ws + (size_t)67108864);
  __hip_bfloat16* Rin = (__hip_bfloat16*)(ws + (size_t)134217728);

  prep_kernel<<<BT, 256, 0, stream>>>(latents, idx, Rin);

  conv3x3_kernel<IN_CH, HID, 8, true, false>
      <<<dim3(BT, HID / 8), 256, 0, stream>>>(Rin, w_in, b_in, Hbuf, nullptr);

  for (int blk = 0; blk < 2; ++blk) {
    const float* w1 = w1s + (size_t)blk * HID * HID * 9;
    const float* w2 = w2s + (size_t)blk * HID * HID * 9;
    conv3x3_kernel<HID, HID, 8, true, false>
        <<<dim3(BT, HID / 8), 256, 0, stream>>>(Hbuf, w1, b1s + blk * HID, Ubuf,
                                                nullptr);
    // residual: H = H + conv(U)  (in-place read-modify-write per element, safe)
    conv3x3_kernel<HID, HID, 8, false, true>
        <<<dim3(BT, HID / 8), 256, 0, stream>>>(Ubuf, w2, b2s + blk * HID, Hbuf,
                                                Hbuf);
  }

  conv_final_kernel<<<BT, 256, 0, stream>>>(Hbuf, w_out, b_out, latents, idx,
                                            dout);
}

// Round 3
// 473.894 us; speedup vs baseline: 11.8065x; 11.8065x over previous
//
#include <hip/hip_runtime.h>
#include <hip/hip_bf16.h>

#define DEVFN __device__ __forceinline__

typedef __attribute__((ext_vector_type(8))) short bf16x8;
typedef __attribute__((ext_vector_type(4))) float f32x4;

constexpr int T = 128, C = 8, K = 9;
constexpr int HW = 1024;   // 32x32
constexpr int BT = 512;    // B*T images
constexpr size_t Z_SIZE = (size_t)BT * C * HW;

// packed-weight element offsets (bf16 elements) inside the pack buffer
constexpr int WP_IN = 0;          // [9][64][32]   = 18432
constexpr int WP_1 = 18432;       // [2][9][64][64]= 73728
constexpr int WP_2 = 92160;       // [2][9][64][64]= 73728
constexpr int WP_OUT = 165888;    // [9][16][64]   = 9216
constexpr int WP_TOT = 175104;

DEVFN ushort f2bs(float x) {
  __hip_bfloat16 h = __float2bfloat16(x);
  ushort u;
  __builtin_memcpy(&u, &h, 2);
  return u;
}
DEVFN float bs2f(ushort u) {
  __hip_bfloat16 h;
  __builtin_memcpy(&h, &u, 2);
  return __bfloat162float(h);
}

DEVFN void interp_params(const int* __restrict__ idx, int b, int t,
                         int& t0, int& t1, float& ar, float& a) {
  int v[K];
#pragma unroll
  for (int k = 0; k < K; ++k) v[k] = idx[b * K + k];
#pragma unroll
  for (int i = 1; i < K; ++i) {
    int key = v[i];
    int j = i - 1;
    while (j >= 0 && v[j] > key) { v[j + 1] = v[j]; --j; }
    v[j + 1] = key;
  }
  int cnt = 0;
#pragma unroll
  for (int k = 0; k < K; ++k) cnt += (v[k] <= t) ? 1 : 0;
  int seg = min(max(cnt - 1, 0), K - 2);
  t0 = v[seg];
  t1 = v[seg + 1];
  ar = (float)(t - t0) / (float)max(t1 - t0, 1);
  a = fminf(fmaxf(ar, 0.f), 1.f);
}

// ---------------------------------------------------------------------------
// weight pack: fp32 [oc][ic][3][3] -> bf16 [tap][oc][ic] (ic/oc zero-padded)
// ---------------------------------------------------------------------------
__global__ __launch_bounds__(256) void pack_weights(
    const float* __restrict__ w_in, const float* __restrict__ w1s,
    const float* __restrict__ w2s, const float* __restrict__ w_out,
    __hip_bfloat16* __restrict__ wp) {
  int e = blockIdx.x * 256 + threadIdx.x;
  if (e >= WP_TOT) return;
  float v;
  if (e < WP_1) {
    int tap = e / 2048, r = e % 2048, oc = r / 32, ic = r % 32;
    v = (ic < 25) ? w_in[((size_t)oc * 25 + ic) * 9 + tap] : 0.f;
  } else if (e < WP_2) {
    int r1 = e - WP_1, blk = r1 / 36864, r = r1 % 36864;
    int tap = r / 4096, r2 = r % 4096, oc = r2 / 64, ic = r2 % 64;
    v = w1s[(((size_t)blk * 64 + oc) * 64 + ic) * 9 + tap];
  } else if (e < WP_OUT) {
    int r1 = e - WP_2, blk = r1 / 36864, r = r1 % 36864;
    int tap = r / 4096, r2 = r % 4096, oc = r2 / 64, ic = r2 % 64;
    v = w2s[(((size_t)blk * 64 + oc) * 64 + ic) * 9 + tap];
  } else {
    int r1 = e - WP_OUT;
    int tap = r1 / 1024, r2 = r1 % 1024, oc = r2 / 64, ic = r2 % 64;
    v = (oc < 9) ? w_out[((size_t)oc * 64 + ic) * 9 + tap] : 0.f;
  }
  wp[e] = __float2bfloat16(v);
}

// ---------------------------------------------------------------------------
// first conv (25->64) with prep FUSED into the LDS staging: builds
// {z_base, z0, z1, alpha} bf16 tile on the fly from fp32 latents.
// Block = 4 waves = 64 oc x 256 px (rows R0..R0+7). IC=32 (25 + zero pad).
// ---------------------------------------------------------------------------
__global__ __launch_bounds__(256) void conv_in_mfma(
    const float* __restrict__ latents, const int* __restrict__ idx,
    const __hip_bfloat16* __restrict__ wp,   // [9][64][32]
    const float* __restrict__ bias,          // [64]
    __hip_bfloat16* __restrict__ out) {      // [512][1024][64]
  constexpr int IC = 32;
  __shared__ __hip_bfloat16 sIn[10 * 32 * IC];  // 20480 B

  const int img = blockIdx.x;
  const int R0 = blockIdx.y * 8;
  const int tid = threadIdx.x;
  const int lane = tid & 63;
  const int wv = tid >> 6;
  const int g = lane >> 4;
  const int ln = lane & 15;
  const int b = img >> 7, t = img & 127;

  int t0, t1;
  float ar, a;
  interp_params(idx, b, t, t0, t1, ar, a);
  const float* z0p = latents + ((size_t)b * T + t0) * C * HW;
  const float* z1p = latents + ((size_t)b * T + t1) * C * HW;
  const ushort ab = f2bs(a);

  // ---- fused stage: one thread per (srow,px) pair writes 4 swizzled slots ----
  for (int pr = tid; pr < 10 * 32; pr += 256) {
    int srow = pr >> 5;
    int px = pr & 31;
    int gy = min(max(R0 + srow - 1, 0), 31);  // clamp; invalid rows predicated
    int p = gy * 32 + px;
    float v0[8], v1[8];
#pragma unroll
    for (int c = 0; c < 8; ++c) {
      v0[c] = z0p[c * HW + p];
      v1[c] = z1p[c * HW + p];
    }
    int base = pr * 64;  // (srow*32+px)*64 bytes; bits 4-5 are zero
    int sw = (px & 3) << 4;
    int4 q;
    // slot 0: z_base
    {
      ushort u[8];
#pragma unroll
      for (int c = 0; c < 8; ++c) u[c] = f2bs((1.f - a) * v0[c] + a * v1[c]);
      q.x = (int)u[0] | ((int)u[1] << 16);
      q.y = (int)u[2] | ((int)u[3] << 16);
      q.z = (int)u[4] | ((int)u[5] << 16);
      q.w = (int)u[6] | ((int)u[7] << 16);
      *(int4*)((char*)sIn + ((base + 0) ^ sw)) = q;
    }
    // slot 1: z0
    {
      ushort u[8];
#pragma unroll
      for (int c = 0; c < 8; ++c) u[c] = f2bs(v0[c]);
      q.x = (int)u[0] | ((int)u[1] << 16);
      q.y = (int)u[2] | ((int)u[3] << 16);
      q.z = (int)u[4] | ((int)u[5] << 16);
      q.w = (int)u[6] | ((int)u[7] << 16);
      *(int4*)((char*)sIn + ((base + 16) ^ sw)) = q;
    }
    // slot 2: z1
    {
      ushort u[8];
#pragma unroll
      for (int c = 0; c < 8; ++c) u[c] = f2bs(v1[c]);
      q.x = (int)u[0] | ((int)u[1] << 16);
      q.y = (int)u[2] | ((int)u[3] << 16);
      q.z = (int)u[4] | ((int)u[5] << 16);
      q.w = (int)u[6] | ((int)u[7] << 16);
      *(int4*)((char*)sIn + ((base + 32) ^ sw)) = q;
    }
    // slot 3: {alpha, 0...}
    {
      q.x = (int)ab;
      q.y = 0;
      q.z = 0;
      q.w = 0;
      *(int4*)((char*)sIn + ((base + 48) ^ sw)) = q;
    }
  }
  __syncthreads();

  f32x4 acc[4][4];
#pragma unroll
  for (int i = 0; i < 4; ++i)
#pragma unroll
    for (int j = 0; j < 4; ++j) acc[i][j] = (f32x4)0.f;

  const int y0 = wv * 2;

#pragma unroll
  for (int tap = 0; tap < 9; ++tap) {
    const int dy = tap / 3 - 1, dx = tap % 3 - 1;
    bf16x8 av[4];
    const __hip_bfloat16* wpt = wp + (size_t)tap * 64 * IC + g * 8;
#pragma unroll
    for (int mt = 0; mt < 4; ++mt)
      av[mt] = *(const bf16x8*)(wpt + (size_t)(mt * 16 + ln) * IC);
    bf16x8 bv[4];
#pragma unroll
    for (int nt = 0; nt < 4; ++nt) {
      int y = y0 + (nt >> 1);
      int x = (nt & 1) * 16 + ln;
      int sy = y + dy;
      int sx = x + dx;
      bool valid = ((unsigned)(R0 + sy) < 32u) && ((unsigned)sx < 32u);
      int sxc = min(max(sx, 0), 31);
      int baddr = (((sy + 1) * 32 + sxc) * IC + g * 8) * 2;
      baddr ^= (sxc & 3) << 4;
      bf16x8 bb = *(const bf16x8*)((const char*)sIn + baddr);
      bf16x8 z = {};
      bv[nt] = valid ? bb : z;
    }
#pragma unroll
    for (int mt = 0; mt < 4; ++mt)
#pragma unroll
      for (int nt = 0; nt < 4; ++nt)
        acc[mt][nt] = __builtin_amdgcn_mfma_f32_16x16x32_bf16(
            av[mt], bv[nt], acc[mt][nt], 0, 0, 0);
  }

  // ---- epilogue: +bias, silu, bf16 store px-major ----
  const size_t outBase = ((size_t)img * HW + (size_t)R0 * 32) * 64;
#pragma unroll
  for (int mt = 0; mt < 4; ++mt) {
    const int oc = mt * 16 + g * 4;
    float bvx[4];
#pragma unroll
    for (int r = 0; r < 4; ++r) bvx[r] = bias[oc + r];
#pragma unroll
    for (int nt = 0; nt < 4; ++nt) {
      const int px = wv * 64 + nt * 16 + ln;
      __hip_bfloat16* op = out + outBase + (size_t)px * 64 + oc;
      ushort4 s;
      float x0 = acc[mt][nt][0] + bvx[0];
      float x1 = acc[mt][nt][1] + bvx[1];
      float x2 = acc[mt][nt][2] + bvx[2];
      float x3 = acc[mt][nt][3] + bvx[3];
      s.x = f2bs(x0 / (1.f + expf(-x0)));
      s.y = f2bs(x1 / (1.f + expf(-x1)));
      s.z = f2bs(x2 / (1.f + expf(-x2)));
      s.w = f2bs(x3 / (1.f + expf(-x3)));
      *(ushort4*)op = s;
    }
  }
}

// ---------------------------------------------------------------------------
// MFMA implicit-GEMM 3x3 conv, IC=OC=64. Activations px-major [img][px][64].
// Block = 4 waves = 64 oc x 256 px (rows R0..R0+7).
// ---------------------------------------------------------------------------
template <bool SILU, bool RESID>
__global__ __launch_bounds__(256) void mfma_conv64(
    const __hip_bfloat16* __restrict__ in,   // [512][1024][64]
    const __hip_bfloat16* __restrict__ wp,   // [9][64][64] bf16
    const float* __restrict__ bias,          // [64]
    __hip_bfloat16* __restrict__ out) {      // [512][1024][64]
  constexpr int IC = 64;
  __shared__ __hip_bfloat16 sIn[10 * 32 * IC];  // 40960 B

  const int img = blockIdx.x;
  const int R0 = blockIdx.y * 8;
  const int tid = threadIdx.x;
  const int lane = tid & 63;
  const int wv = tid >> 6;
  const int g = lane >> 4;
  const int ln = lane & 15;

  // ---- stage (reg-staged so the LDS write can be swizzled) ----
  {
    const size_t imgBase = (size_t)img * HW * IC;
    constexpr int CHUNKS = 10 * 32 * 8;
    for (int ch = tid; ch < CHUNKS; ch += 256) {
      int srow = ch >> 8;
      int rem = ch & 255;
      int px = rem >> 3;
      int slot = rem & 7;
      int gy = min(max(R0 + srow - 1, 0), 31);
      int4 v = *(const int4*)(in + imgBase + (size_t)(gy * 32 + px) * IC + slot * 8);
      int dst = (ch * 16) ^ ((px & 7) << 4);
      *(int4*)((char*)sIn + dst) = v;
    }
  }
  __syncthreads();

  f32x4 acc[4][4];
#pragma unroll
  for (int i = 0; i < 4; ++i)
#pragma unroll
    for (int j = 0; j < 4; ++j) acc[i][j] = (f32x4)0.f;

  const int y0 = wv * 2;

#pragma unroll
  for (int tap = 0; tap < 9; ++tap) {
    const int dy = tap / 3 - 1, dx = tap % 3 - 1;
#pragma unroll
    for (int c = 0; c < 2; ++c) {
      bf16x8 av[4];
      const __hip_bfloat16* wpt = wp + (size_t)tap * 64 * IC + c * 32 + g * 8;
#pragma unroll
      for (int mt = 0; mt < 4; ++mt)
        av[mt] = *(const bf16x8*)(wpt + (size_t)(mt * 16 + ln) * IC);
      bf16x8 bv[4];
#pragma unroll
      for (int nt = 0; nt < 4; ++nt) {
        int y = y0 + (nt >> 1);
        int x = (nt & 1) * 16 + ln;
        int sy = y + dy;
        int sx = x + dx;
        bool valid = ((unsigned)(R0 + sy) < 32u) && ((unsigned)sx < 32u);
        int sxc = min(max(sx, 0), 31);
        int baddr = (((sy + 1) * 32 + sxc) * IC + c * 32 + g * 8) * 2;
        baddr ^= (sxc & 7) << 4;
        bf16x8 bb = *(const bf16x8*)((const char*)sIn + baddr);
        bf16x8 z = {};
        bv[nt] = valid ? bb : z;
      }
#pragma unroll
      for (int mt = 0; mt < 4; ++mt)
#pragma unroll
        for (int nt = 0; nt < 4; ++nt)
          acc[mt][nt] = __builtin_amdgcn_mfma_f32_16x16x32_bf16(
              av[mt], bv[nt], acc[mt][nt], 0, 0, 0);
    }
  }

  // ---- epilogue: +bias, silu / resid-add, bf16 store px-major ----
  const size_t outBase = ((size_t)img * HW + (size_t)R0 * 32) * 64;
#pragma unroll
  for (int mt = 0; mt < 4; ++mt) {
    const int oc = mt * 16 + g * 4;
    float bvx[4];
#pragma unroll
    for (int r = 0; r < 4; ++r) bvx[r] = bias[oc + r];
#pragma unroll
    for (int nt = 0; nt < 4; ++nt) {
      const int px = wv * 64 + nt * 16 + ln;
      __hip_bfloat16* op = out + outBase + (size_t)px * 64 + oc;
      float v[4];
#pragma unroll
      for (int r = 0; r < 4; ++r) {
        float x = acc[mt][nt][r] + bvx[r];
        if (SILU) x = x / (1.f + expf(-x));
        v[r] = x;
      }
      if (RESID) {
        ushort4 h = *(const ushort4*)op;
        v[0] += bs2f(h.x);
        v[1] += bs2f(h.y);
        v[2] += bs2f(h.z);
        v[3] += bs2f(h.w);
      }
      ushort4 s;
      s.x = f2bs(v[0]);
      s.y = f2bs(v[1]);
      s.z = f2bs(v[2]);
      s.w = f2bs(v[3]);
      *(ushort4*)op = s;
    }
  }
}

// ---------------------------------------------------------------------------
// final conv 64 -> 16(9 used) fused with z_hat / conf epilogue
// ---------------------------------------------------------------------------
__global__ __launch_bounds__(256) void mfma_conv_final(
    const __hip_bfloat16* __restrict__ in,   // H [512][1024][64]
    const __hip_bfloat16* __restrict__ wp,   // [9][16][64]
    const float* __restrict__ bias,          // [9]
    const float* __restrict__ latents, const int* __restrict__ idx,
    float* __restrict__ dout) {
  constexpr int IC = 64;
  __shared__ __hip_bfloat16 sIn[10 * 32 * 64];
  __shared__ float sOut[256][17];

  const int img = blockIdx.x;
  const int R0 = blockIdx.y * 8;
  const int tid = threadIdx.x;
  const int lane = tid & 63;
  const int wv = tid >> 6;
  const int g = lane >> 4;
  const int ln = lane & 15;

  {
    const size_t imgBase = (size_t)img * HW * IC;
    for (int ch = tid; ch < 10 * 32 * 8; ch += 256) {
      int srow = ch >> 8;
      int rem = ch & 255;
      int px = rem >> 3;
      int slot = rem & 7;
      int gy = min(max(R0 + srow - 1, 0), 31);
      int4 v = *(const int4*)(in + imgBase + (size_t)(gy * 32 + px) * IC + slot * 8);
      int dst = (ch * 16) ^ ((px & 7) << 4);
      *(int4*)((char*)sIn + dst) = v;
    }
  }
  __syncthreads();

  f32x4 acc[4];
#pragma unroll
  for (int j = 0; j < 4; ++j) acc[j] = (f32x4)0.f;

  const int y0 = wv * 2;
#pragma unroll
  for (int tap = 0; tap < 9; ++tap) {
    const int dy = tap / 3 - 1, dx = tap % 3 - 1;
#pragma unroll
    for (int c = 0; c < 2; ++c) {
      bf16x8 av = *(const bf16x8*)(wp + ((size_t)tap * 16 + ln) * 64 + c * 32 + g * 8);
      bf16x8 bv[4];
#pragma unroll
      for (int nt = 0; nt < 4; ++nt) {
        int y = y0 + (nt >> 1);
        int x = (nt & 1) * 16 + ln;
        int sy = y + dy;
        int sx = x + dx;
        bool valid = ((unsigned)(R0 + sy) < 32u) && ((unsigned)sx < 32u);
        int sxc = min(max(sx, 0), 31);
        int baddr = (((sy + 1) * 32 + sxc) * IC + c * 32 + g * 8) * 2;
        baddr ^= (sxc & 7) << 4;
        bf16x8 bb = *(const bf16x8*)((const char*)sIn + baddr);
        bf16x8 z = {};
        bv[nt] = valid ? bb : z;
      }
#pragma unroll
      for (int nt = 0; nt < 4; ++nt)
        acc[nt] = __builtin_amdgcn_mfma_f32_16x16x32_bf16(av, bv[nt], acc[nt], 0, 0, 0);
    }
  }

  // phase 1: accum (+bias) -> LDS [px][oc]
  const int oc0 = g * 4;
#pragma unroll
  for (int nt = 0; nt < 4; ++nt) {
    const int pxl = wv * 64 + nt * 16 + ln;
#pragma unroll
    for (int r = 0; r < 4; ++r) {
      const int oc = oc0 + r;
      float bvv = (oc < 9) ? bias[oc] : 0.f;
      sOut[pxl][oc] = acc[nt][r] + bvv;
    }
  }
  __syncthreads();

  // phase 2: fused z_hat / conf epilogue, one thread per pixel
  const int b = img >> 7, t = img & 127;
  int t0, t1;
  float ar, a;
  interp_params(idx, b, t, t0, t1, ar, a);
  const bool interior = (ar > 0.f) && (ar < 1.f);
  const float aa = a * (1.f - a);
  const float* z0p = latents + ((size_t)b * T + t0) * C * HW;
  const float* z1p = latents + ((size_t)b * T + t1) * C * HW;
  const int px = R0 * 32 + tid;
#pragma unroll
  for (int c = 0; c < 8; ++c) {
    float res = sOut[tid][c];
    float v0 = z0p[c * HW + px], v1 = z1p[c * HW + px];
    float zb = (1.f - a) * v0 + a * v1;
    dout[((size_t)img * C + c) * HW + px] = zb + aa * res;
  }
  float unc = 1.f / (1.f + expf(-sOut[tid][8]));
  float conf = interior ? fminf(fmaxf(1.f - unc, 0.f), 1.f) : 1.f;
  dout[Z_SIZE + (size_t)img * HW + px] = conf;
}

// ---------------------------------------------------------------------------
// launch
// ---------------------------------------------------------------------------
extern "C" void kernel_launch(void* const* d_in, const int* in_sizes, int n_in,
                              void* d_out, int out_size, void* d_ws,
                              size_t ws_size, hipStream_t stream) {
  const float* latents = (const float*)d_in[0];
  const int* idx = (const int*)d_in[1];
  const float* w_in = (const float*)d_in[2];
  const float* b_in = (const float*)d_in[3];
  const float* w1s = (const float*)d_in[4];
  const float* b1s = (const float*)d_in[5];
  const float* w2s = (const float*)d_in[6];
  const float* b2s = (const float*)d_in[7];
  const float* w_out = (const float*)d_in[8];
  const float* b_out = (const float*)d_in[9];
  float* dout = (float*)d_out;

  // ws layout: A [0,64MiB) ; Bf [64MiB,128MiB) ; packed weights @128MiB
  char* ws = (char*)d_ws;
  __hip_bfloat16* A = (__hip_bfloat16*)ws;
  __hip_bfloat16* Bf = (__hip_bfloat16*)(ws + (size_t)67108864);
  __hip_bfloat16* wpk = (__hip_bfloat16*)(ws + (size_t)134217728);

  pack_weights<<<(WP_TOT + 255) / 256, 256, 0, stream>>>(w_in, w1s, w2s, w_out,
                                                         wpk);

  conv_in_mfma<<<dim3(BT, 4), 256, 0, stream>>>(latents, idx, wpk + WP_IN, b_in,
                                                A);

  for (int blk = 0; blk < 2; ++blk) {
    mfma_conv64<true, false><<<dim3(BT, 4), 256, 0, stream>>>(
        A, wpk + WP_1 + blk * 36864, b1s + blk * 64, Bf);
    mfma_conv64<false, true><<<dim3(BT, 4), 256, 0, stream>>>(
        Bf, wpk + WP_2 + blk * 36864, b2s + blk * 64, A);
  }

  mfma_conv_final<<<dim3(BT, 4), 256, 0, stream>>>(A, wpk + WP_OUT, b_out,
                                                   latents, idx, dout);
}

// Round 4
// 322.727 us; speedup vs baseline: 17.3367x; 1.4684x over previous
//
#include <hip/hip_runtime.h>
#include <hip/hip_bf16.h>

#define DEVFN __device__ __forceinline__

typedef __attribute__((ext_vector_type(8))) short bf16x8;
typedef __attribute__((ext_vector_type(4))) float f32x4;

constexpr int T = 128, C = 8, K = 9;
constexpr int HW = 1024;   // 32x32
constexpr int BT = 512;    // B*T images
constexpr size_t Z_SIZE = (size_t)BT * C * HW;

// LDS image buffer geometry: site = (sy, sx) in [0,34)x[0,34), 64 ch bf16 = 128 B
constexpr int ROW_B = 34 * 128;    // 4352 bytes per site-row (multiple of 128)
constexpr int BUF_B = 34 * ROW_B;  // 147,968 bytes

// fragment-packed weights (bf16 element offsets): [tap][c][mt][lane][8]
constexpr int WP_IN = 0;            // 9*1*4*64*8 = 18432
constexpr int WP_W1_0 = 18432;      // 9*2*4*64*8 = 36864
constexpr int WP_W2_0 = 55296;
constexpr int WP_W1_1 = 92160;
constexpr int WP_W2_1 = 129024;
constexpr int WP_OUT = 165888;      // 9*2*1*64*8 = 9216
constexpr int WP_TOT = 175104;

DEVFN ushort f2bs(float x) {
  __hip_bfloat16 h = __float2bfloat16(x);
  ushort u;
  __builtin_memcpy(&u, &h, 2);
  return u;
}
DEVFN float bs2f(ushort u) {
  __hip_bfloat16 h;
  __builtin_memcpy(&h, &u, 2);
  return __bfloat162float(h);
}

DEVFN void interp_params(const int* __restrict__ idx, int b, int t,
                         int& t0, int& t1, float& ar, float& a) {
  int v[K];
#pragma unroll
  for (int k = 0; k < K; ++k) v[k] = idx[b * K + k];
#pragma unroll
  for (int i = 1; i < K; ++i) {
    int key = v[i];
    int j = i - 1;
    while (j >= 0 && v[j] > key) { v[j + 1] = v[j]; --j; }
    v[j + 1] = key;
  }
  int cnt = 0;
#pragma unroll
  for (int k = 0; k < K; ++k) cnt += (v[k] <= t) ? 1 : 0;
  int seg = min(max(cnt - 1, 0), K - 2);
  t0 = v[seg];
  t1 = v[seg + 1];
  ar = (float)(t - t0) / (float)max(t1 - t0, 1);
  a = fminf(fmaxf(ar, 0.f), 1.f);
}

// ---------------------------------------------------------------------------
// weight pack: fragment order [tap][c][mt][lane][8]:
//   element = W[oc = mt*16 + (lane&15)][ic = c*32 + (lane>>4)*8 + e][tap]
// so an A-fragment load is 64 lanes x consecutive 16B = one coalesced 1KB.
// ---------------------------------------------------------------------------
__global__ __launch_bounds__(256) void pack_weights(
    const float* __restrict__ w_in, const float* __restrict__ w1s,
    const float* __restrict__ w2s, const float* __restrict__ w_out,
    __hip_bfloat16* __restrict__ wp) {
  int e = blockIdx.x * 256 + threadIdx.x;
  if (e >= WP_TOT) return;
  float v;
  if (e < WP_W1_0) {  // conv_in: [9][1][4][64][8], IC=32 (25 real)
    int tap = e / 2048;
    int r2 = e % 2048;
    int mt = r2 / 512;
    int lane = (r2 / 8) & 63;
    int el = e & 7;
    int oc = mt * 16 + (lane & 15);
    int ic = (lane >> 4) * 8 + el;
    v = (ic < 25) ? w_in[((size_t)oc * 25 + ic) * 9 + tap] : 0.f;
  } else if (e < WP_OUT) {  // 4 x conv64: [9][2][4][64][8]
    int r = e - WP_W1_0;
    int layer = r / 36864;  // 0:w1 blk0, 1:w2 blk0, 2:w1 blk1, 3:w2 blk1
    int r2 = r % 36864;
    int tap = r2 / 4096;
    int c = (r2 / 2048) & 1;
    int mt = (r2 / 512) & 3;
    int lane = (r2 / 8) & 63;
    int el = r2 & 7;
    int oc = mt * 16 + (lane & 15);
    int ic = c * 32 + (lane >> 4) * 8 + el;
    const float* src = (layer & 1) ? w2s : w1s;
    int blk = layer >> 1;
    v = src[(((size_t)blk * 64 + oc) * 64 + ic) * 9 + tap];
  } else {  // final: [9][2][1][64][8], OC=16 (9 real)
    int r2 = e - WP_OUT;
    int tap = r2 / 1024;
    int c = (r2 / 512) & 1;
    int lane = (r2 / 8) & 63;
    int el = r2 & 7;
    int oc = lane & 15;
    int ic = c * 32 + (lane >> 4) * 8 + el;
    v = (oc < 9) ? w_out[((size_t)oc * 64 + ic) * 9 + tap] : 0.f;
  }
  wp[e] = __float2bfloat16(v);
}

// ---------------------------------------------------------------------------
// conv compute: reads zero-halo LDS tile, accumulates into acc[2][MT][4].
// bases: 6 precomputed swizzled byte offsets (d = dx+1, c); everything else
// is a compile-time ds_read offset. dy-reuse: 12 B-chunks feed MT*3*8 MFMAs.
// ---------------------------------------------------------------------------
template <int CK, int MT>
DEVFN void conv_compute(const char* sBuf, const __hip_bfloat16* __restrict__ wpf,
                        const int (&base)[3][2], int lane,
                        f32x4 (&acc)[2][MT][4]) {
#pragma unroll
  for (int c = 0; c < CK; ++c) {
#pragma unroll
    for (int d = 0; d < 3; ++d) {
      bf16x8 bv[6][2];
#pragma unroll
      for (int j = 0; j < 6; ++j) {
#pragma unroll
        for (int xh = 0; xh < 2; ++xh)
          bv[j][xh] = *(const bf16x8*)(sBuf + base[d][c] + xh * 2048 + j * ROW_B);
      }
#pragma unroll
      for (int mt = 0; mt < MT; ++mt) {
#pragma unroll
        for (int dyi = 0; dyi < 3; ++dyi) {
          const int tap = dyi * 3 + d;
          bf16x8 av = *(const bf16x8*)(wpf + (((tap * CK + c) * MT + mt) * 64 + lane) * 8);
#pragma unroll
          for (int tl = 0; tl < 2; ++tl) {
#pragma unroll
            for (int oy = 0; oy < 2; ++oy) {
              const int j = 2 * tl + oy + dyi;
#pragma unroll
              for (int xh = 0; xh < 2; ++xh)
                acc[tl][mt][oy * 2 + xh] = __builtin_amdgcn_mfma_f32_16x16x32_bf16(
                    av, bv[j][xh], acc[tl][mt][oy * 2 + xh], 0, 0, 0);
            }
          }
        }
      }
    }
  }
}

DEVFN void h_read(const char* sBuf, const int (&wbase)[4], ushort4 (&hs)[2][4][4]) {
#pragma unroll
  for (int tl = 0; tl < 2; ++tl)
#pragma unroll
    for (int mt = 0; mt < 4; ++mt)
#pragma unroll
      for (int nt = 0; nt < 4; ++nt) {
        const int off = (nt & 1) * 2048 + (2 * tl + (nt >> 1) + 1) * ROW_B;
        hs[tl][mt][nt] = *(const ushort4*)(sBuf + wbase[mt] + off);
      }
}

DEVFN void layer_write_silu(char* sBuf, const int (&wbase)[4],
                            const float* __restrict__ bias, int g,
                            const f32x4 (&acc)[2][4][4]) {
#pragma unroll
  for (int tl = 0; tl < 2; ++tl)
#pragma unroll
    for (int mt = 0; mt < 4; ++mt) {
      const int oc0 = mt * 16 + g * 4;
#pragma unroll
      for (int nt = 0; nt < 4; ++nt) {
        const int off = (nt & 1) * 2048 + (2 * tl + (nt >> 1) + 1) * ROW_B;
        ushort4 s;
        float x0 = acc[tl][mt][nt][0] + bias[oc0 + 0];
        float x1 = acc[tl][mt][nt][1] + bias[oc0 + 1];
        float x2 = acc[tl][mt][nt][2] + bias[oc0 + 2];
        float x3 = acc[tl][mt][nt][3] + bias[oc0 + 3];
        s.x = f2bs(x0 / (1.f + expf(-x0)));
        s.y = f2bs(x1 / (1.f + expf(-x1)));
        s.z = f2bs(x2 / (1.f + expf(-x2)));
        s.w = f2bs(x3 / (1.f + expf(-x3)));
        *(ushort4*)(sBuf + wbase[mt] + off) = s;
      }
    }
}

DEVFN void layer_write_resid(char* sBuf, const int (&wbase)[4],
                             const float* __restrict__ bias, int g,
                             const f32x4 (&acc)[2][4][4],
                             const ushort4 (&hs)[2][4][4]) {
#pragma unroll
  for (int tl = 0; tl < 2; ++tl)
#pragma unroll
    for (int mt = 0; mt < 4; ++mt) {
      const int oc0 = mt * 16 + g * 4;
#pragma unroll
      for (int nt = 0; nt < 4; ++nt) {
        const int off = (nt & 1) * 2048 + (2 * tl + (nt >> 1) + 1) * ROW_B;
        ushort4 s;
        s.x = f2bs(acc[tl][mt][nt][0] + bias[oc0 + 0] + bs2f(hs[tl][mt][nt].x));
        s.y = f2bs(acc[tl][mt][nt][1] + bias[oc0 + 1] + bs2f(hs[tl][mt][nt].y));
        s.z = f2bs(acc[tl][mt][nt][2] + bias[oc0 + 2] + bs2f(hs[tl][mt][nt].z));
        s.w = f2bs(acc[tl][mt][nt][3] + bias[oc0 + 3] + bs2f(hs[tl][mt][nt].w));
        *(ushort4*)(sBuf + wbase[mt] + off) = s;
      }
    }
}

// ---------------------------------------------------------------------------
// mega kernel: one block per image; whole refiner with LDS-resident state.
// 8 waves; wave wv owns output rows 4*wv..4*wv+3 (2 tiles of 2 rows x 32 px).
// ---------------------------------------------------------------------------
__global__ __launch_bounds__(512, 2) void mega_kernel(
    const float* __restrict__ latents, const int* __restrict__ idx,
    const __hip_bfloat16* __restrict__ wpk, const float* __restrict__ b_in,
    const float* __restrict__ b1s, const float* __restrict__ b2s,
    const float* __restrict__ b_out, float* __restrict__ dout) {
  __shared__ __align__(16) char sBuf[BUF_B];

  const int img = blockIdx.x;
  const int tid = threadIdx.x;
  const int lane = tid & 63;
  const int wv = tid >> 6;
  const int g = lane >> 4;
  const int ln = lane & 15;
  const int r0 = wv * 4;
  const int b = img >> 7, t = img & 127;

  int t0, t1;
  float ar, a;
  interp_params(idx, b, t, t0, t1, ar, a);
  const float* z0p = latents + ((size_t)b * T + t0) * C * HW;
  const float* z1p = latents + ((size_t)b * T + t1) * C * HW;

  // ---- phase 0: prep (zero halo, build 25-ch input in slots 0..3) ----
  for (int hsi = tid; hsi < 132; hsi += 512) {
    int sy, sx;
    if (hsi < 34) { sy = 0; sx = hsi; }
    else if (hsi < 68) { sy = 33; sx = hsi - 34; }
    else { int r = hsi - 68; sy = 1 + (r >> 1); sx = (r & 1) * 33; }
    int4* p4 = (int4*)(sBuf + sy * ROW_B + sx * 128);
#pragma unroll
    for (int q = 0; q < 8; ++q) p4[q] = int4{0, 0, 0, 0};
  }
  {
    const ushort ab = f2bs(a);
#pragma unroll
    for (int it = 0; it < 2; ++it) {
      const int si = it * 512 + tid;
      const int y = si >> 5, x = si & 31;
      const int sy = y + 1, sx = x + 1;
      const int key = (sx & 7) << 4;
      char* rowp = sBuf + sy * ROW_B + sx * 128;
      float v0[8], v1[8];
#pragma unroll
      for (int c2 = 0; c2 < 8; ++c2) {
        v0[c2] = z0p[c2 * HW + si];
        v1[c2] = z1p[c2 * HW + si];
      }
      ushort u[8];
      int4 q;
#pragma unroll
      for (int c2 = 0; c2 < 8; ++c2) u[c2] = f2bs((1.f - a) * v0[c2] + a * v1[c2]);
      q.x = (int)u[0] | ((int)u[1] << 16); q.y = (int)u[2] | ((int)u[3] << 16);
      q.z = (int)u[4] | ((int)u[5] << 16); q.w = (int)u[6] | ((int)u[7] << 16);
      *(int4*)(rowp + (0 ^ key)) = q;
#pragma unroll
      for (int c2 = 0; c2 < 8; ++c2) u[c2] = f2bs(v0[c2]);
      q.x = (int)u[0] | ((int)u[1] << 16); q.y = (int)u[2] | ((int)u[3] << 16);
      q.z = (int)u[4] | ((int)u[5] << 16); q.w = (int)u[6] | ((int)u[7] << 16);
      *(int4*)(rowp + (16 ^ key)) = q;
#pragma unroll
      for (int c2 = 0; c2 < 8; ++c2) u[c2] = f2bs(v1[c2]);
      q.x = (int)u[0] | ((int)u[1] << 16); q.y = (int)u[2] | ((int)u[3] << 16);
      q.z = (int)u[4] | ((int)u[5] << 16); q.w = (int)u[6] | ((int)u[7] << 16);
      *(int4*)(rowp + (32 ^ key)) = q;
      q.x = (int)ab; q.y = 0; q.z = 0; q.w = 0;
      *(int4*)(rowp + (48 ^ key)) = q;
    }
  }
  __syncthreads();

  // ---- precomputed LDS addressing ----
  // read bases: addr = base[d][c] + xh*2048 + j*ROW_B   (j = srow index 0..5)
  int base[3][2];
#pragma unroll
  for (int d = 0; d < 3; ++d)
#pragma unroll
    for (int c = 0; c < 2; ++c)
      base[d][c] = r0 * ROW_B +
                   (((ln + d) * 128 + c * 64 + g * 16) ^ (((ln + d) & 7) << 4));
  // write bases: addr = wbase[mt] + (nt&1)*2048 + (2*tl+(nt>>1)+1)*ROW_B
  const int wkey = ((ln + 1) & 7) << 4;
  int wbase[4];
#pragma unroll
  for (int mt = 0; mt < 4; ++mt)
    wbase[mt] = r0 * ROW_B + (ln + 1) * 128 + ((mt * 32 + g * 8) ^ wkey);

  // ---- L1: conv_in (25->64), silu ----
  {
    f32x4 acc[2][4][4];
#pragma unroll
    for (int tl = 0; tl < 2; ++tl)
#pragma unroll
      for (int mt = 0; mt < 4; ++mt)
#pragma unroll
        for (int nt = 0; nt < 4; ++nt) acc[tl][mt][nt] = (f32x4)0.f;
    conv_compute<1, 4>(sBuf, wpk + WP_IN, base, lane, acc);
    __syncthreads();
    layer_write_silu(sBuf, wbase, b_in, g, acc);
    __syncthreads();
  }

  // ---- residual blocks: u = silu(conv1(h)); h = h + conv2(u) ----
#pragma unroll 1
  for (int blk = 0; blk < 2; ++blk) {
    const __hip_bfloat16* wp1 = wpk + (blk ? WP_W1_1 : WP_W1_0);
    const __hip_bfloat16* wp2 = wpk + (blk ? WP_W2_1 : WP_W2_0);
    ushort4 hsave[2][4][4];
    {
      f32x4 acc[2][4][4];
#pragma unroll
      for (int tl = 0; tl < 2; ++tl)
#pragma unroll
        for (int mt = 0; mt < 4; ++mt)
#pragma unroll
          for (int nt = 0; nt < 4; ++nt) acc[tl][mt][nt] = (f32x4)0.f;
      conv_compute<2, 4>(sBuf, wp1, base, lane, acc);
      h_read(sBuf, wbase, hsave);  // save h at own px before overwrite
      __syncthreads();
      layer_write_silu(sBuf, wbase, b1s + blk * 64, g, acc);
      __syncthreads();
    }
    {
      f32x4 acc[2][4][4];
#pragma unroll
      for (int tl = 0; tl < 2; ++tl)
#pragma unroll
        for (int mt = 0; mt < 4; ++mt)
#pragma unroll
          for (int nt = 0; nt < 4; ++nt) acc[tl][mt][nt] = (f32x4)0.f;
      conv_compute<2, 4>(sBuf, wp2, base, lane, acc);
      __syncthreads();
      layer_write_resid(sBuf, wbase, b2s + blk * 64, g, acc, hsave);
      __syncthreads();
    }
  }

  // ---- final conv (64->16, 9 real), raw acc -> LDS slots 0..1 ----
  {
    f32x4 acc[2][1][4];
#pragma unroll
    for (int tl = 0; tl < 2; ++tl)
#pragma unroll
      for (int nt = 0; nt < 4; ++nt) acc[tl][0][nt] = (f32x4)0.f;
    conv_compute<2, 1>(sBuf, wpk + WP_OUT, base, lane, acc);
    __syncthreads();
#pragma unroll
    for (int tl = 0; tl < 2; ++tl)
#pragma unroll
      for (int nt = 0; nt < 4; ++nt) {
        const int off = (nt & 1) * 2048 + (2 * tl + (nt >> 1) + 1) * ROW_B;
        ushort4 s;
        s.x = f2bs(acc[tl][0][nt][0]);
        s.y = f2bs(acc[tl][0][nt][1]);
        s.z = f2bs(acc[tl][0][nt][2]);
        s.w = f2bs(acc[tl][0][nt][3]);
        *(ushort4*)(sBuf + wbase[0] + off) = s;
      }
    __syncthreads();
  }

  // ---- fused epilogue: z_hat / conf from LDS res + fp32 latents ----
  const bool interior = (ar > 0.f) && (ar < 1.f);
  const float aa = a * (1.f - a);
#pragma unroll
  for (int q = 0; q < 2; ++q) {
    const int px = q * 512 + tid;
    const int y = px >> 5, x = px & 31;
    const int sy = y + 1, sx = x + 1;
    const int key = (sx & 7) << 4;
    const char* rp = sBuf + sy * ROW_B + sx * 128;
    bf16x8 r8 = *(const bf16x8*)(rp + (0 ^ key));
    int r9i = *(const int*)(rp + (16 ^ key));
    float res[9];
#pragma unroll
    for (int e = 0; e < 8; ++e) res[e] = bs2f((ushort)r8[e]);
    res[8] = bs2f((ushort)(r9i & 0xffff));
#pragma unroll
    for (int c2 = 0; c2 < 8; ++c2) {
      float v0 = z0p[c2 * HW + px], v1 = z1p[c2 * HW + px];
      float zb = (1.f - a) * v0 + a * v1;
      dout[((size_t)img * C + c2) * HW + px] = zb + aa * (res[c2] + b_out[c2]);
    }
    float unc = 1.f / (1.f + expf(-(res[8] + b_out[8])));
    float conf = interior ? fminf(fmaxf(1.f - unc, 0.f), 1.f) : 1.f;
    dout[Z_SIZE + (size_t)img * HW + px] = conf;
  }
}

// ---------------------------------------------------------------------------
// launch
// ---------------------------------------------------------------------------
extern "C" void kernel_launch(void* const* d_in, const int* in_sizes, int n_in,
                              void* d_out, int out_size, void* d_ws,
                              size_t ws_size, hipStream_t stream) {
  const float* latents = (const float*)d_in[0];
  const int* idx = (const int*)d_in[1];
  const float* w_in = (const float*)d_in[2];
  const float* b_in = (const float*)d_in[3];
  const float* w1s = (const float*)d_in[4];
  const float* b1s = (const float*)d_in[5];
  const float* w2s = (const float*)d_in[6];
  const float* b2s = (const float*)d_in[7];
  const float* w_out = (const float*)d_in[8];
  const float* b_out = (const float*)d_in[9];
  float* dout = (float*)d_out;

  __hip_bfloat16* wpk = (__hip_bfloat16*)d_ws;  // 350,208 B

  pack_weights<<<(WP_TOT + 255) / 256, 256, 0, stream>>>(w_in, w1s, w2s, w_out,
                                                         wpk);
  mega_kernel<<<BT, 512, 0, stream>>>(latents, idx, wpk, b_in, b1s, b2s, b_out,
                                      dout);
}

// Round 5
// 322.122 us; speedup vs baseline: 17.3693x; 1.0019x over previous
//
#include <hip/hip_runtime.h>
#include <hip/hip_bf16.h>

#define DEVFN __device__ __forceinline__

typedef __attribute__((ext_vector_type(8))) short bf16x8;
typedef __attribute__((ext_vector_type(4))) float f32x4;

constexpr int T = 128, C = 8, K = 9;
constexpr int HW = 1024;   // 32x32
constexpr int BT = 512;    // B*T images
constexpr size_t Z_SIZE = (size_t)BT * C * HW;

// LDS image buffer geometry: site = (sy, sx) in [0,34)x[0,34), 64 ch bf16 = 128 B
constexpr int ROW_B = 34 * 128;    // 4352 bytes per site-row (multiple of 128)
constexpr int BUF_B = 34 * ROW_B;  // 147,968 bytes

// fragment-packed weights (bf16 element offsets): [tap][c][mt][lane][8]
constexpr int WP_IN = 0;            // 9*1*4*64*8 = 18432
constexpr int WP_W1_0 = 18432;      // 9*2*4*64*8 = 36864
constexpr int WP_W2_0 = 55296;
constexpr int WP_W1_1 = 92160;
constexpr int WP_W2_1 = 129024;
constexpr int WP_OUT = 165888;      // 9*2*1*64*8 = 9216
constexpr int WP_TOT = 175104;

DEVFN ushort f2bs(float x) {
  __hip_bfloat16 h = __float2bfloat16(x);
  ushort u;
  __builtin_memcpy(&u, &h, 2);
  return u;
}
DEVFN float bs2f(ushort u) {
  __hip_bfloat16 h;
  __builtin_memcpy(&h, &u, 2);
  return __bfloat162float(h);
}

DEVFN void interp_params(const int* __restrict__ idx, int b, int t,
                         int& t0, int& t1, float& ar, float& a) {
  int v[K];
#pragma unroll
  for (int k = 0; k < K; ++k) v[k] = idx[b * K + k];
#pragma unroll
  for (int i = 1; i < K; ++i) {
    int key = v[i];
    int j = i - 1;
    while (j >= 0 && v[j] > key) { v[j + 1] = v[j]; --j; }
    v[j + 1] = key;
  }
  int cnt = 0;
#pragma unroll
  for (int k = 0; k < K; ++k) cnt += (v[k] <= t) ? 1 : 0;
  int seg = min(max(cnt - 1, 0), K - 2);
  t0 = v[seg];
  t1 = v[seg + 1];
  ar = (float)(t - t0) / (float)max(t1 - t0, 1);
  a = fminf(fmaxf(ar, 0.f), 1.f);
}

// ---------------------------------------------------------------------------
// weight pack: fragment order [tap][c][mt][lane][8]:
//   element = W[oc = mt*16 + (lane&15)][ic = c*32 + (lane>>4)*8 + e][tap]
// so an A-fragment load is 64 lanes x consecutive 16B = one coalesced 1KB.
// ---------------------------------------------------------------------------
__global__ __launch_bounds__(256) void pack_weights(
    const float* __restrict__ w_in, const float* __restrict__ w1s,
    const float* __restrict__ w2s, const float* __restrict__ w_out,
    __hip_bfloat16* __restrict__ wp) {
  int e = blockIdx.x * 256 + threadIdx.x;
  if (e >= WP_TOT) return;
  float v;
  if (e < WP_W1_0) {  // conv_in: [9][1][4][64][8], IC=32 (25 real)
    int tap = e / 2048;
    int r2 = e % 2048;
    int mt = r2 / 512;
    int lane = (r2 / 8) & 63;
    int el = e & 7;
    int oc = mt * 16 + (lane & 15);
    int ic = (lane >> 4) * 8 + el;
    v = (ic < 25) ? w_in[((size_t)oc * 25 + ic) * 9 + tap] : 0.f;
  } else if (e < WP_OUT) {  // 4 x conv64: [9][2][4][64][8]
    int r = e - WP_W1_0;
    int layer = r / 36864;  // 0:w1 blk0, 1:w2 blk0, 2:w1 blk1, 3:w2 blk1
    int r2 = r % 36864;
    int tap = r2 / 4096;
    int c = (r2 / 2048) & 1;
    int mt = (r2 / 512) & 3;
    int lane = (r2 / 8) & 63;
    int el = r2 & 7;
    int oc = mt * 16 + (lane & 15);
    int ic = c * 32 + (lane >> 4) * 8 + el;
    const float* src = (layer & 1) ? w2s : w1s;
    int blk = layer >> 1;
    v = src[(((size_t)blk * 64 + oc) * 64 + ic) * 9 + tap];
  } else {  // final: [9][2][1][64][8], OC=16 (9 real)
    int r2 = e - WP_OUT;
    int tap = r2 / 1024;
    int c = (r2 / 512) & 1;
    int lane = (r2 / 8) & 63;
    int el = r2 & 7;
    int oc = lane & 15;
    int ic = c * 32 + (lane >> 4) * 8 + el;
    v = (oc < 9) ? w_out[((size_t)oc * 64 + ic) * 9 + tap] : 0.f;
  }
  wp[e] = __float2bfloat16(v);
}

// ---------------------------------------------------------------------------
// conv compute: reads zero-halo LDS tile, accumulates into acc[2][MT][4].
// bases: 6 precomputed swizzled byte offsets (d = dx+1, c); everything else
// is a compile-time ds_read offset. dy-reuse: 12 B-chunks feed MT*3*8 MFMAs.
// ---------------------------------------------------------------------------
template <int CK, int MT>
DEVFN void conv_compute(const char* sBuf, const __hip_bfloat16* __restrict__ wpf,
                        const int (&base)[3][2], int lane,
                        f32x4 (&acc)[2][MT][4]) {
#pragma unroll
  for (int c = 0; c < CK; ++c) {
#pragma unroll
    for (int d = 0; d < 3; ++d) {
      bf16x8 bv[6][2];
#pragma unroll
      for (int j = 0; j < 6; ++j) {
#pragma unroll
        for (int xh = 0; xh < 2; ++xh)
          bv[j][xh] = *(const bf16x8*)(sBuf + base[d][c] + xh * 2048 + j * ROW_B);
      }
#pragma unroll
      for (int mt = 0; mt < MT; ++mt) {
#pragma unroll
        for (int dyi = 0; dyi < 3; ++dyi) {
          const int tap = dyi * 3 + d;
          bf16x8 av = *(const bf16x8*)(wpf + (((tap * CK + c) * MT + mt) * 64 + lane) * 8);
#pragma unroll
          for (int tl = 0; tl < 2; ++tl) {
#pragma unroll
            for (int oy = 0; oy < 2; ++oy) {
              const int j = 2 * tl + oy + dyi;
#pragma unroll
              for (int xh = 0; xh < 2; ++xh)
                acc[tl][mt][oy * 2 + xh] = __builtin_amdgcn_mfma_f32_16x16x32_bf16(
                    av, bv[j][xh], acc[tl][mt][oy * 2 + xh], 0, 0, 0);
            }
          }
        }
      }
    }
  }
}

DEVFN void h_read(const char* sBuf, const int (&wbase)[4], ushort4 (&hs)[2][4][4]) {
#pragma unroll
  for (int tl = 0; tl < 2; ++tl)
#pragma unroll
    for (int mt = 0; mt < 4; ++mt)
#pragma unroll
      for (int nt = 0; nt < 4; ++nt) {
        const int off = (nt & 1) * 2048 + (2 * tl + (nt >> 1) + 1) * ROW_B;
        hs[tl][mt][nt] = *(const ushort4*)(sBuf + wbase[mt] + off);
      }
}

DEVFN void layer_write_silu(char* sBuf, const int (&wbase)[4],
                            const float* __restrict__ bias, int g,
                            const f32x4 (&acc)[2][4][4]) {
#pragma unroll
  for (int tl = 0; tl < 2; ++tl)
#pragma unroll
    for (int mt = 0; mt < 4; ++mt) {
      const int oc0 = mt * 16 + g * 4;
#pragma unroll
      for (int nt = 0; nt < 4; ++nt) {
        const int off = (nt & 1) * 2048 + (2 * tl + (nt >> 1) + 1) * ROW_B;
        ushort4 s;
        float x0 = acc[tl][mt][nt][0] + bias[oc0 + 0];
        float x1 = acc[tl][mt][nt][1] + bias[oc0 + 1];
        float x2 = acc[tl][mt][nt][2] + bias[oc0 + 2];
        float x3 = acc[tl][mt][nt][3] + bias[oc0 + 3];
        s.x = f2bs(x0 / (1.f + expf(-x0)));
        s.y = f2bs(x1 / (1.f + expf(-x1)));
        s.z = f2bs(x2 / (1.f + expf(-x2)));
        s.w = f2bs(x3 / (1.f + expf(-x3)));
        *(ushort4*)(sBuf + wbase[mt] + off) = s;
      }
    }
}

DEVFN void layer_write_resid(char* sBuf, const int (&wbase)[4],
                             const float* __restrict__ bias, int g,
                             const f32x4 (&acc)[2][4][4],
                             const ushort4 (&hs)[2][4][4]) {
#pragma unroll
  for (int tl = 0; tl < 2; ++tl)
#pragma unroll
    for (int mt = 0; mt < 4; ++mt) {
      const int oc0 = mt * 16 + g * 4;
#pragma unroll
      for (int nt = 0; nt < 4; ++nt) {
        const int off = (nt & 1) * 2048 + (2 * tl + (nt >> 1) + 1) * ROW_B;
        ushort4 s;
        s.x = f2bs(acc[tl][mt][nt][0] + bias[oc0 + 0] + bs2f(hs[tl][mt][nt].x));
        s.y = f2bs(acc[tl][mt][nt][1] + bias[oc0 + 1] + bs2f(hs[tl][mt][nt].y));
        s.z = f2bs(acc[tl][mt][nt][2] + bias[oc0 + 2] + bs2f(hs[tl][mt][nt].z));
        s.w = f2bs(acc[tl][mt][nt][3] + bias[oc0 + 3] + bs2f(hs[tl][mt][nt].w));
        *(ushort4*)(sBuf + wbase[mt] + off) = s;
      }
    }
}

// ---------------------------------------------------------------------------
// mega kernel: one block per image; whole refiner with LDS-resident state.
// 8 waves; wave wv owns output rows 4*wv..4*wv+3 (2 tiles of 2 rows x 32 px).
// LDS (148 KB) caps occupancy at ONE block/CU = 2 waves/SIMD regardless of
// registers, so let the allocator use the full 256-VGPR budget (round 4's
// __launch_bounds__(512,2) capped VGPRs at 128 -> ~300 MB scratch spill).
// ---------------------------------------------------------------------------
__global__ __launch_bounds__(512)
__attribute__((amdgpu_waves_per_eu(1, 2))) void mega_kernel(
    const float* __restrict__ latents, const int* __restrict__ idx,
    const __hip_bfloat16* __restrict__ wpk, const float* __restrict__ b_in,
    const float* __restrict__ b1s, const float* __restrict__ b2s,
    const float* __restrict__ b_out, float* __restrict__ dout) {
  __shared__ __align__(16) char sBuf[BUF_B];

  const int img = blockIdx.x;
  const int tid = threadIdx.x;
  const int lane = tid & 63;
  const int wv = tid >> 6;
  const int g = lane >> 4;
  const int ln = lane & 15;
  const int r0 = wv * 4;
  const int b = img >> 7, t = img & 127;

  int t0, t1;
  float ar, a;
  interp_params(idx, b, t, t0, t1, ar, a);
  const float* z0p = latents + ((size_t)b * T + t0) * C * HW;
  const float* z1p = latents + ((size_t)b * T + t1) * C * HW;

  // ---- phase 0: prep (zero halo, build 25-ch input in slots 0..3) ----
  for (int hsi = tid; hsi < 132; hsi += 512) {
    int sy, sx;
    if (hsi < 34) { sy = 0; sx = hsi; }
    else if (hsi < 68) { sy = 33; sx = hsi - 34; }
    else { int r = hsi - 68; sy = 1 + (r >> 1); sx = (r & 1) * 33; }
    int4* p4 = (int4*)(sBuf + sy * ROW_B + sx * 128);
#pragma unroll
    for (int q = 0; q < 8; ++q) p4[q] = int4{0, 0, 0, 0};
  }
  {
    const ushort ab = f2bs(a);
#pragma unroll
    for (int it = 0; it < 2; ++it) {
      const int si = it * 512 + tid;
      const int y = si >> 5, x = si & 31;
      const int sy = y + 1, sx = x + 1;
      const int key = (sx & 7) << 4;
      char* rowp = sBuf + sy * ROW_B + sx * 128;
      float v0[8], v1[8];
#pragma unroll
      for (int c2 = 0; c2 < 8; ++c2) {
        v0[c2] = z0p[c2 * HW + si];
        v1[c2] = z1p[c2 * HW + si];
      }
      ushort u[8];
      int4 q;
#pragma unroll
      for (int c2 = 0; c2 < 8; ++c2) u[c2] = f2bs((1.f - a) * v0[c2] + a * v1[c2]);
      q.x = (int)u[0] | ((int)u[1] << 16); q.y = (int)u[2] | ((int)u[3] << 16);
      q.z = (int)u[4] | ((int)u[5] << 16); q.w = (int)u[6] | ((int)u[7] << 16);
      *(int4*)(rowp + (0 ^ key)) = q;
#pragma unroll
      for (int c2 = 0; c2 < 8; ++c2) u[c2] = f2bs(v0[c2]);
      q.x = (int)u[0] | ((int)u[1] << 16); q.y = (int)u[2] | ((int)u[3] << 16);
      q.z = (int)u[4] | ((int)u[5] << 16); q.w = (int)u[6] | ((int)u[7] << 16);
      *(int4*)(rowp + (16 ^ key)) = q;
#pragma unroll
      for (int c2 = 0; c2 < 8; ++c2) u[c2] = f2bs(v1[c2]);
      q.x = (int)u[0] | ((int)u[1] << 16); q.y = (int)u[2] | ((int)u[3] << 16);
      q.z = (int)u[4] | ((int)u[5] << 16); q.w = (int)u[6] | ((int)u[7] << 16);
      *(int4*)(rowp + (32 ^ key)) = q;
      q.x = (int)ab; q.y = 0; q.z = 0; q.w = 0;
      *(int4*)(rowp + (48 ^ key)) = q;
    }
  }
  __syncthreads();

  // ---- precomputed LDS addressing ----
  // read bases: addr = base[d][c] + xh*2048 + j*ROW_B   (j = srow index 0..5)
  int base[3][2];
#pragma unroll
  for (int d = 0; d < 3; ++d)
#pragma unroll
    for (int c = 0; c < 2; ++c)
      base[d][c] = r0 * ROW_B +
                   (((ln + d) * 128 + c * 64 + g * 16) ^ (((ln + d) & 7) << 4));
  // write bases: addr = wbase[mt] + (nt&1)*2048 + (2*tl+(nt>>1)+1)*ROW_B
  const int wkey = ((ln + 1) & 7) << 4;
  int wbase[4];
#pragma unroll
  for (int mt = 0; mt < 4; ++mt)
    wbase[mt] = r0 * ROW_B + (ln + 1) * 128 + ((mt * 32 + g * 8) ^ wkey);

  // ---- L1: conv_in (25->64), silu ----
  {
    f32x4 acc[2][4][4];
#pragma unroll
    for (int tl = 0; tl < 2; ++tl)
#pragma unroll
      for (int mt = 0; mt < 4; ++mt)
#pragma unroll
        for (int nt = 0; nt < 4; ++nt) acc[tl][mt][nt] = (f32x4)0.f;
    conv_compute<1, 4>(sBuf, wpk + WP_IN, base, lane, acc);
    __syncthreads();
    layer_write_silu(sBuf, wbase, b_in, g, acc);
    __syncthreads();
  }

  // ---- residual blocks: u = silu(conv1(h)); h = h + conv2(u) ----
#pragma unroll 1
  for (int blk = 0; blk < 2; ++blk) {
    const __hip_bfloat16* wp1 = wpk + (blk ? WP_W1_1 : WP_W1_0);
    const __hip_bfloat16* wp2 = wpk + (blk ? WP_W2_1 : WP_W2_0);
    ushort4 hsave[2][4][4];
    {
      f32x4 acc[2][4][4];
#pragma unroll
      for (int tl = 0; tl < 2; ++tl)
#pragma unroll
        for (int mt = 0; mt < 4; ++mt)
#pragma unroll
          for (int nt = 0; nt < 4; ++nt) acc[tl][mt][nt] = (f32x4)0.f;
      conv_compute<2, 4>(sBuf, wp1, base, lane, acc);
      h_read(sBuf, wbase, hsave);  // save h at own px before overwrite
      __syncthreads();
      layer_write_silu(sBuf, wbase, b1s + blk * 64, g, acc);
      __syncthreads();
    }
    {
      f32x4 acc[2][4][4];
#pragma unroll
      for (int tl = 0; tl < 2; ++tl)
#pragma unroll
        for (int mt = 0; mt < 4; ++mt)
#pragma unroll
          for (int nt = 0; nt < 4; ++nt) acc[tl][mt][nt] = (f32x4)0.f;
      conv_compute<2, 4>(sBuf, wp2, base, lane, acc);
      __syncthreads();
      layer_write_resid(sBuf, wbase, b2s + blk * 64, g, acc, hsave);
      __syncthreads();
    }
  }

  // ---- final conv (64->16, 9 real), raw acc -> LDS slots 0..1 ----
  {
    f32x4 acc[2][1][4];
#pragma unroll
    for (int tl = 0; tl < 2; ++tl)
#pragma unroll
      for (int nt = 0; nt < 4; ++nt) acc[tl][0][nt] = (f32x4)0.f;
    conv_compute<2, 1>(sBuf, wpk + WP_OUT, base, lane, acc);
    __syncthreads();
#pragma unroll
    for (int tl = 0; tl < 2; ++tl)
#pragma unroll
      for (int nt = 0; nt < 4; ++nt) {
        const int off = (nt & 1) * 2048 + (2 * tl + (nt >> 1) + 1) * ROW_B;
        ushort4 s;
        s.x = f2bs(acc[tl][0][nt][0]);
        s.y = f2bs(acc[tl][0][nt][1]);
        s.z = f2bs(acc[tl][0][nt][2]);
        s.w = f2bs(acc[tl][0][nt][3]);
        *(ushort4*)(sBuf + wbase[0] + off) = s;
      }
    __syncthreads();
  }

  // ---- fused epilogue: z_hat / conf from LDS res + fp32 latents ----
  const bool interior = (ar > 0.f) && (ar < 1.f);
  const float aa = a * (1.f - a);
#pragma unroll
  for (int q = 0; q < 2; ++q) {
    const int px = q * 512 + tid;
    const int y = px >> 5, x = px & 31;
    const int sy = y + 1, sx = x + 1;
    const int key = (sx & 7) << 4;
    const char* rp = sBuf + sy * ROW_B + sx * 128;
    bf16x8 r8 = *(const bf16x8*)(rp + (0 ^ key));
    int r9i = *(const int*)(rp + (16 ^ key));
    float res[9];
#pragma unroll
    for (int e = 0; e < 8; ++e) res[e] = bs2f((ushort)r8[e]);
    res[8] = bs2f((ushort)(r9i & 0xffff));
#pragma unroll
    for (int c2 = 0; c2 < 8; ++c2) {
      float v0 = z0p[c2 * HW + px], v1 = z1p[c2 * HW + px];
      float zb = (1.f - a) * v0 + a * v1;
      dout[((size_t)img * C + c2) * HW + px] = zb + aa * (res[c2] + b_out[c2]);
    }
    float unc = 1.f / (1.f + expf(-(res[8] + b_out[8])));
    float conf = interior ? fminf(fmaxf(1.f - unc, 0.f), 1.f) : 1.f;
    dout[Z_SIZE + (size_t)img * HW + px] = conf;
  }
}

// ---------------------------------------------------------------------------
// launch
// ---------------------------------------------------------------------------
extern "C" void kernel_launch(void* const* d_in, const int* in_sizes, int n_in,
                              void* d_out, int out_size, void* d_ws,
                              size_t ws_size, hipStream_t stream) {
  const float* latents = (const float*)d_in[0];
  const int* idx = (const int*)d_in[1];
  const float* w_in = (const float*)d_in[2];
  const float* b_in = (const float*)d_in[3];
  const float* w1s = (const float*)d_in[4];
  const float* b1s = (const float*)d_in[5];
  const float* w2s = (const float*)d_in[6];
  const float* b2s = (const float*)d_in[7];
  const float* w_out = (const float*)d_in[8];
  const float* b_out = (const float*)d_in[9];
  float* dout = (float*)d_out;

  __hip_bfloat16* wpk = (__hip_bfloat16*)d_ws;  // 350,208 B

  pack_weights<<<(WP_TOT + 255) / 256, 256, 0, stream>>>(w_in, w1s, w2s, w_out,
                                                         wpk);
  mega_kernel<<<BT, 512, 0, stream>>>(latents, idx, wpk, b_in, b1s, b2s, b_out,
                                      dout);
}